// Round 4
// baseline (52.969 us; speedup 1.0000x reference)
//
#include <hip/hip_runtime.h>

// Deimv2LQE: out = scores + MLP(top4-softmax-stats(pred_corners))
// 262144 rows; per row 132 f32 (4 corners x 33 bins).
// R4: barrier-free 1-wave blocks, 64 rows/block in 4 substages of 16 rows,
//     software-pipelined reg staging. Stats held in registers (constant-
//     indexed P5[4]) and bounced through the SAME 8448 B LDS buffer after
//     the stage is dead -> LDS/block 13824->8448, occupancy 11->16 waves/CU.
//     MLP lane-per-row with wave-uniform weight indices (s_load path).

#define THREADS 64
#define ROWS 64
#define SUB 16   // rows per substage

struct P5 { float p0, p1, p2, p3, pm; };

__global__ __launch_bounds__(THREADS)
void lqe_kernel(const float* __restrict__ scores,
                const float* __restrict__ pc,
                const float* __restrict__ w1,
                const float* __restrict__ b1,
                const float* __restrict__ w2,
                const float* __restrict__ b2,
                float* __restrict__ out)
{
    // 8448 B: stage for one 16-row substage (2112 floats), reused at the end
    // as the 64x21 stat bounce (1344 floats).
    __shared__ float sm[SUB * 132];

    const int l = threadIdx.x;
    const long long rowBase = (long long)blockIdx.x * ROWS;

    const float myScore = scores[rowBase + l];   // prefetch early

    const float4* src = (const float4*)(pc + rowBase * 132); // 2112 f4/block
    float4* dst4 = (float4*)sm;

    // 528 f4 per substage = 8/lane + 16 tail
    auto load_sub = [&](float4 (&r)[8], float4& t, int s) {
        const float4* p = src + s * 528;
        #pragma unroll
        for (int i = 0; i < 8; ++i) r[i] = p[l + i * 64];
        if (l < 16) t = p[512 + l];
    };
    auto write_sub = [&](float4 (&r)[8], float4& t) {
        #pragma unroll
        for (int i = 0; i < 8; ++i) dst4[l + i * 64] = r[i];
        if (l < 16) dst4[512 + l] = t;
    };
    // lane handles corner: row_local = l>>2, corner = l&3; LDS addr 33*l
    // (odd stride -> <=2-way bank aliasing, free).
    auto compute_sub = [&]() -> P5 {
        const float* v = sm + l * 33;
        float x[33];
        #pragma unroll
        for (int k = 0; k < 33; ++k) x[k] = v[k];

        // top-4 descending (t0..t3), branchless insertion network
        float t0 = x[0], t1 = x[1], t2 = x[2], t3 = x[3];
        float a;
        a = fmaxf(t0, t1); t1 = fminf(t0, t1); t0 = a;
        a = fmaxf(t2, t3); t3 = fminf(t2, t3); t2 = a;
        a = fmaxf(t0, t2); t2 = fminf(t0, t2); t0 = a;
        a = fmaxf(t1, t3); t3 = fminf(t1, t3); t1 = a;
        a = fmaxf(t1, t2); t2 = fminf(t1, t2); t1 = a;
        #pragma unroll
        for (int k = 4; k < 33; ++k) {
            float xx = x[k];
            a = fmaxf(t0, xx); xx = fminf(t0, xx); t0 = a;
            a = fmaxf(t1, xx); xx = fminf(t1, xx); t1 = a;
            a = fmaxf(t2, xx); xx = fminf(t2, xx); t2 = a;
            t3 = fmaxf(t3, xx);
        }

        float ssum = 0.f;
        #pragma unroll
        for (int k = 0; k < 33; ++k) ssum += __expf(x[k] - t0);
        const float inv = 1.0f / ssum;
        P5 r;
        r.p0 = inv;
        r.p1 = __expf(t1 - t0) * inv;
        r.p2 = __expf(t2 - t0) * inv;
        r.p3 = __expf(t3 - t0) * inv;
        r.pm = 0.25f * (r.p0 + r.p1 + r.p2 + r.p3);
        return r;
    };

    float4 ra[8], rb[8], ta, tb;
    P5 stv[4];   // constant-indexed only -> SROA to registers

    // software pipeline: both first substages' loads in flight before the
    // first LDS write (counted vmcnt), then overlap load s+1 with compute s.
    // In-order DS semantics within a wave make read-before-overwrite safe.
    load_sub(ra, ta, 0);
    load_sub(rb, tb, 1);
    write_sub(ra, ta);
    stv[0] = compute_sub();
    write_sub(rb, tb);
    load_sub(ra, ta, 2);
    stv[1] = compute_sub();
    write_sub(ra, ta);
    load_sub(rb, tb, 3);
    stv[2] = compute_sub();
    write_sub(rb, tb);
    stv[3] = compute_sub();

    // ---- stat bounce through the (now dead) stage buffer ----
    // write: substage-major layout; read: row-major for lane-per-row MLP.
    // stride 21 (odd) -> near-conflict-free.
    {
        const int rbase = (l >> 2) * 21 + (l & 3) * 5;
        #pragma unroll
        for (int s = 0; s < 4; ++s) {
            float* sd = sm + s * (SUB * 21) + rbase;
            sd[0] = stv[s].p0; sd[1] = stv[s].p1; sd[2] = stv[s].p2;
            sd[3] = stv[s].p3; sd[4] = stv[s].pm;
        }
    }

    float st[20];
    #pragma unroll
    for (int k = 0; k < 20; ++k) st[k] = sm[l * 21 + k];

    // ---- MLP: lane-per-row; weight indices wave-uniform -> s_load ----
    float acc = 0.f;
    #pragma unroll
    for (int jc = 0; jc < 4; ++jc) {
        float h[16];
        #pragma unroll
        for (int j = 0; j < 16; ++j) h[j] = b1[jc * 16 + j];
        #pragma unroll
        for (int k = 0; k < 20; ++k) {
            #pragma unroll
            for (int j = 0; j < 16; ++j)
                h[j] = fmaf(st[k], w1[k * 64 + jc * 16 + j], h[j]);
        }
        #pragma unroll
        for (int j = 0; j < 16; ++j)
            acc = fmaf(fmaxf(h[j], 0.f), w2[jc * 16 + j], acc);
    }

    out[rowBase + l] = myScore + acc + b2[0];
}

extern "C" void kernel_launch(void* const* d_in, const int* in_sizes, int n_in,
                              void* d_out, int out_size, void* d_ws, size_t ws_size,
                              hipStream_t stream) {
    const float* scores = (const float*)d_in[0];
    const float* pc     = (const float*)d_in[1];
    const float* w1     = (const float*)d_in[2];
    const float* b1     = (const float*)d_in[3];
    const float* w2     = (const float*)d_in[4];
    const float* b2     = (const float*)d_in[5];
    float* out = (float*)d_out;

    const int rows = out_size;          // 262144
    const int blocks = rows / ROWS;     // 4096
    lqe_kernel<<<blocks, THREADS, 0, stream>>>(scores, pc, w1, b1, w2, b2, out);
}